// Round 3
// baseline (253.033 us; speedup 1.0000x reference)
//
#include <hip/hip_runtime.h>
#include <hip/hip_bf16.h>
#include <math.h>

#define NPIX 4096   // 64*64
#define DIMC 48
#define NB 2

typedef __attribute__((ext_vector_type(8))) short short8;
typedef __attribute__((ext_vector_type(4))) float floatx4;

static __device__ inline short f2bf(float f) {
    union { float f; unsigned u; } v; v.f = f;
    unsigned r = (v.u + 0x7FFFu + ((v.u >> 16) & 1u)) >> 16;
    return (short)r;
}

// ---------------- LN over channels + 1x1 conv ----------------
// grid: (64 pixel-tiles, 24 o-groups, NB), block 64
__global__ void k_ln_conv(const float* __restrict__ x,
                          const float* __restrict__ lw, const float* __restrict__ lb,
                          const float* __restrict__ cw, const float* __restrict__ cb,
                          float* __restrict__ out, int OC) {
    int p = blockIdx.x * 64 + threadIdx.x;
    int og = blockIdx.y;
    int b = blockIdx.z;
    const float* xb = x + (size_t)b * DIMC * NPIX;
    float v[DIMC];
    float mu = 0.f;
#pragma unroll
    for (int c = 0; c < DIMC; c++) { v[c] = xb[(size_t)c * NPIX + p]; mu += v[c]; }
    mu *= (1.f / DIMC);
    float var = 0.f;
#pragma unroll
    for (int c = 0; c < DIMC; c++) { float d = v[c] - mu; var += d * d; }
    var *= (1.f / DIMC);
    float rs = rsqrtf(var + 1e-5f);
#pragma unroll
    for (int c = 0; c < DIMC; c++) v[c] = (v[c] - mu) * rs * lw[c] + lb[c];
    int chunk = OC / gridDim.y;
    int o0 = og * chunk;
    for (int o = o0; o < o0 + chunk; o++) {
        float acc = cb[o];
        const float* wrow = cw + (size_t)o * DIMC;
#pragma unroll
        for (int c = 0; c < DIMC; c++) acc += wrow[c] * v[c];
        out[((size_t)b * OC + o) * NPIX + p] = acc;
    }
}

// ---------------- depthwise 3x3, SAME ----------------
__global__ void k_dw3(const float* __restrict__ in, const float* __restrict__ w,
                      const float* __restrict__ bias, float* __restrict__ out, int C) {
    int idx = blockIdx.x * 256 + threadIdx.x;
    int total = NB * C * NPIX;
    if (idx >= total) return;
    int xx = idx & 63;
    int yy = (idx >> 6) & 63;
    int bc = idx >> 12;          // b*C + c
    int c = bc % C;
    const float* ip = in + (size_t)bc * NPIX;
    const float* wp = w + (size_t)c * 9;
    float acc = bias[c];
#pragma unroll
    for (int ky = 0; ky < 3; ky++) {
        int y2 = yy + ky - 1;
        if ((unsigned)y2 < 64u) {
#pragma unroll
            for (int kx = 0; kx < 3; kx++) {
                int x2 = xx + kx - 1;
                if ((unsigned)x2 < 64u) acc += ip[y2 * 64 + x2] * wp[ky * 3 + kx];
            }
        }
    }
    out[idx] = acc;
}

// ---------------- split heads, l2norm q,k (fold temp), emit bf16 MFMA layouts --------
// Qbf,Kbf: [bh][4096][32] row-major (d padded 24->32 with zeros)
// Vbf:     [bh][32][4096] channel-major (channels 24..31 zero)
// grid: (64, 2, NB), block 64
__global__ void k_heads(const float* __restrict__ qkv, const float* __restrict__ temp,
                        short* __restrict__ Qbf, short* __restrict__ Kbf,
                        short* __restrict__ Vbf) {
    int n = blockIdx.x * 64 + threadIdx.x;
    int h = blockIdx.y;
    int b = blockIdx.z;
    int bh = b * 2 + h;
    const float* base = qkv + (size_t)b * 144 * NPIX;
    float q[24], k[24], vv[24];
    float sq = 0.f, sk = 0.f;
#pragma unroll
    for (int c = 0; c < 24; c++) {
        q[c] = base[(size_t)(h * 24 + c) * NPIX + n];       sq += q[c] * q[c];
        k[c] = base[(size_t)(48 + h * 24 + c) * NPIX + n];  sk += k[c] * k[c];
        vv[c] = base[(size_t)(96 + h * 24 + c) * NPIX + n];
    }
    float rq = temp[h] / fmaxf(sqrtf(sq), 1e-12f);
    float rk = 1.f / fmaxf(sqrtf(sk), 1e-12f);
    short qs[32], ks[32];
#pragma unroll
    for (int c = 0; c < 24; c++) {
        qs[c] = f2bf(q[c] * rq);
        ks[c] = f2bf(k[c] * rk);
    }
#pragma unroll
    for (int c = 24; c < 32; c++) { qs[c] = 0; ks[c] = 0; }
    size_t ro = ((size_t)bh * NPIX + n) * 32;
#pragma unroll
    for (int i = 0; i < 4; i++) {
        short8 sq8, sk8;
#pragma unroll
        for (int j = 0; j < 8; j++) { sq8[j] = qs[i * 8 + j]; sk8[j] = ks[i * 8 + j]; }
        *(short8*)(Qbf + ro + i * 8) = sq8;
        *(short8*)(Kbf + ro + i * 8) = sk8;
    }
#pragma unroll
    for (int c = 0; c < 24; c++)
        Vbf[((size_t)bh * 32 + c) * NPIX + n] = f2bf(vv[c]);
#pragma unroll
    for (int c = 24; c < 32; c++)
        Vbf[((size_t)bh * 32 + c) * NPIX + n] = 0;
}

// ---------------- MFMA flash attention, key-split inside block ----------------
// grid: (qt=256, bh=4), block 256. Wave w covers keys w*1024..+1023 for 16 q-rows.
// No softmax max needed: q,k unit-norm, |score| <= temp. Cross-wave combine in LDS.
__global__ __launch_bounds__(256) void k_attn_mfma(const short* __restrict__ Qbf,
                                                   const short* __restrict__ Kbf,
                                                   const short* __restrict__ Vbf,
                                                   float* __restrict__ O) {
    int qt = blockIdx.x;
    int bh = blockIdx.y;
    int t = threadIdx.x;
    int w = t >> 6;
    int lane = t & 63;
    int l15 = lane & 15;
    int quad = lane >> 4;

    __shared__ unsigned P[4][16][20];     // bf16 pairs, row = q-row, dword col = key pair
    __shared__ float Ored[4][16][33];
    __shared__ float Lred[4][16];

    int qrow0 = qt * 16;
    const short* qptr = Qbf + ((size_t)bh * NPIX + qrow0 + l15) * 32 + quad * 8;
    short8 aq = *(const short8*)qptr;

    // b0: even keys (kb + 2*l15), b1: odd keys (kb + 2*l15 + 1)
    const short* kbase = Kbf + ((size_t)bh * NPIX + 2 * l15) * 32 + quad * 8;
    const short* vbase = Vbf + ((size_t)bh * 32 + l15) * NPIX + quad * 8;

    floatx4 zf = {0.f, 0.f, 0.f, 0.f};
    floatx4 o0 = zf, o1 = zf;
    float ls[4] = {0.f, 0.f, 0.f, 0.f};
    int key0 = w * 1024;

    short8 b0 = *(const short8*)(kbase + (size_t)key0 * 32);
    short8 b1 = *(const short8*)(kbase + (size_t)key0 * 32 + 32);
    short8 v0 = *(const short8*)(vbase + key0);
    short8 v1 = *(const short8*)(vbase + key0 + 16 * NPIX);

    for (int kt = 0; kt < 32; kt++) {
        int kbn = key0 + ((kt + 1) & 31) * 32;   // wraps on last iter (harmless)
        short8 nb0 = *(const short8*)(kbase + (size_t)kbn * 32);
        short8 nb1 = *(const short8*)(kbase + (size_t)kbn * 32 + 32);
        short8 nv0 = *(const short8*)(vbase + kbn);
        short8 nv1 = *(const short8*)(vbase + kbn + 16 * NPIX);

        floatx4 s0 = __builtin_amdgcn_mfma_f32_16x16x32_bf16(aq, b0, zf, 0, 0, 0);
        floatx4 s1 = __builtin_amdgcn_mfma_f32_16x16x32_bf16(aq, b1, zf, 0, 0, 0);
#pragma unroll
        for (int r = 0; r < 4; r++) {
            float p0 = __expf(s0[r]);   // col = key kb+2*l15
            float p1 = __expf(s1[r]);   // col = key kb+2*l15+1
            ls[r] += p0 + p1;
            __hip_bfloat162 pk = __float22bfloat162_rn(make_float2(p0, p1));
            P[w][quad * 4 + r][l15] = *(unsigned*)&pk;
        }
        // A-frag: row l15, key offsets quad*8..+7 (contiguous bf16 shorts)
        short8 ap = *(const short8*)((const short*)&P[w][l15][0] + quad * 8);
        o0 = __builtin_amdgcn_mfma_f32_16x16x32_bf16(ap, v0, o0, 0, 0, 0);
        o1 = __builtin_amdgcn_mfma_f32_16x16x32_bf16(ap, v1, o1, 0, 0, 0);
        b0 = nb0; b1 = nb1; v0 = nv0; v1 = nv1;
    }
    // row sums across the 16 lanes of each quad
#pragma unroll
    for (int m = 1; m < 16; m <<= 1) {
#pragma unroll
        for (int r = 0; r < 4; r++) ls[r] += __shfl_xor(ls[r], m, 64);
    }
#pragma unroll
    for (int r = 0; r < 4; r++) {
        Ored[w][quad * 4 + r][l15] = o0[r];
        Ored[w][quad * 4 + r][16 + l15] = o1[r];
    }
    if (l15 == 0) {
#pragma unroll
        for (int r = 0; r < 4; r++) Lred[w][quad * 4 + r] = ls[r];
    }
    __syncthreads();
    // combine 4 waves, normalize, write O[b][c][n]
    int b = bh >> 1, h = bh & 1;
    int n16 = t & 15;
    int c = t >> 4;   // 0..15
    float l = Lred[0][n16] + Lred[1][n16] + Lred[2][n16] + Lred[3][n16];
    float rl = 1.f / l;
    float acc = Ored[0][n16][c] + Ored[1][n16][c] + Ored[2][n16][c] + Ored[3][n16][c];
    O[((size_t)b * DIMC + h * 24 + c) * NPIX + qrow0 + n16] = acc * rl;
    if (t < 128) {
        int c2 = 16 + c;   // 16..23
        float acc2 = Ored[0][n16][c2] + Ored[1][n16][c2] + Ored[2][n16][c2] + Ored[3][n16][c2];
        O[((size_t)b * DIMC + h * 24 + c2) * NPIX + qrow0 + n16] = acc2 * rl;
    }
}

// ---------------- 1x1 proj + residual ----------------
// grid: (64 tiles, NB, 12 ogroups), block 64
__global__ void k_proj(const float* __restrict__ x, const float* __restrict__ O,
                       const float* __restrict__ w, const float* __restrict__ bias,
                       float* __restrict__ x1) {
    int p = blockIdx.x * 64 + threadIdx.x;
    int b = blockIdx.y;
    int o0 = blockIdx.z * 4;
    float v[48];
#pragma unroll
    for (int i = 0; i < 48; i++) v[i] = O[((size_t)b * 48 + i) * NPIX + p];
    for (int o = o0; o < o0 + 4; o++) {
        float acc = bias[o];
        const float* wrow = w + (size_t)o * 48;
#pragma unroll
        for (int i = 0; i < 48; i++) acc += wrow[i] * v[i];
        size_t idx = ((size_t)b * 48 + o) * NPIX + p;
        x1[idx] = x[idx] + acc;
    }
}

// ---------------- exact GELU gate ----------------
__global__ void k_gate(const float* __restrict__ f, float* __restrict__ y) {
    int idx = blockIdx.x * 256 + threadIdx.x;
    int total = NB * 96 * NPIX;
    if (idx >= total) return;
    int b = idx / (96 * NPIX);
    int rem = idx - b * 96 * NPIX;
    float a = f[(size_t)b * 192 * NPIX + rem];
    float gte = f[(size_t)b * 192 * NPIX + 96 * NPIX + rem];
    float ge = 0.5f * a * (1.f + erff(a * 0.70710678118654752f));
    y[idx] = ge * gte;
}

// ---------------- 1x1 fo + residual ----------------
// grid: (64 tiles, NB, 12 ogroups), block 64
__global__ void k_fo(const float* __restrict__ x1, const float* __restrict__ y,
                     const float* __restrict__ w, const float* __restrict__ bias,
                     float* __restrict__ out) {
    int p = blockIdx.x * 64 + threadIdx.x;
    int b = blockIdx.y;
    int o0 = blockIdx.z * 4;
    float v[96];
#pragma unroll
    for (int i = 0; i < 96; i++) v[i] = y[((size_t)b * 96 + i) * NPIX + p];
    for (int o = o0; o < o0 + 4; o++) {
        float acc = bias[o];
        const float* wrow = w + (size_t)o * 96;
#pragma unroll
        for (int i = 0; i < 96; i++) acc += wrow[i] * v[i];
        size_t idx = ((size_t)b * 48 + o) * NPIX + p;
        out[idx] = x1[idx] + acc;
    }
}

extern "C" void kernel_launch(void* const* d_in, const int* in_sizes, int n_in,
                              void* d_out, int out_size, void* d_ws, size_t ws_size,
                              hipStream_t stream) {
    const float* x       = (const float*)d_in[0];
    const float* n1w     = (const float*)d_in[1];
    const float* n1b     = (const float*)d_in[2];
    const float* qkv_w   = (const float*)d_in[3];
    const float* qkv_b   = (const float*)d_in[4];
    const float* qkvdw_w = (const float*)d_in[5];
    const float* qkvdw_b = (const float*)d_in[6];
    const float* temp    = (const float*)d_in[7];
    const float* proj_w  = (const float*)d_in[8];
    const float* proj_b  = (const float*)d_in[9];
    const float* n2w     = (const float*)d_in[10];
    const float* n2b     = (const float*)d_in[11];
    const float* fi_w    = (const float*)d_in[12];
    const float* fi_b    = (const float*)d_in[13];
    const float* fdw_w   = (const float*)d_in[14];
    const float* fdw_b   = (const float*)d_in[15];
    const float* fo_w    = (const float*)d_in[16];
    const float* fo_b    = (const float*)d_in[17];

    float* ws = (float*)d_ws;
    float* qkv_pre = ws;                        // 1179648 f
    float* qkv     = qkv_pre + 1179648;         // 1179648 f
    float* base2   = qkv + 1179648;
    short* Qbf     = (short*)base2;             // 524288 s = 262144 f
    short* Kbf     = Qbf + 524288;              // 524288 s
    short* Vbf     = Kbf + 524288;              // 524288 s
    float* O       = base2 + 786432;            // 393216 f
    float* x1      = O + 393216;                // 393216 f
    float* f_pre   = x1 + 393216;               // 1572864 f
    float* f       = f_pre + 1572864;           // 1572864 f
    float* y       = f + 1572864;               // 786432 f

    // ---- attention branch ----
    {
        dim3 g(64, 24, NB);
        k_ln_conv<<<g, 64, 0, stream>>>(x, n1w, n1b, qkv_w, qkv_b, qkv_pre, 144);
    }
    {
        int total = NB * 144 * NPIX;
        k_dw3<<<(total + 255) / 256, 256, 0, stream>>>(qkv_pre, qkvdw_w, qkvdw_b, qkv, 144);
    }
    {
        dim3 g(64, 2, NB);
        k_heads<<<g, 64, 0, stream>>>(qkv, temp, Qbf, Kbf, Vbf);
    }
    {
        dim3 g(256, 4);
        k_attn_mfma<<<g, 256, 0, stream>>>(Qbf, Kbf, Vbf, O);
    }
    {
        dim3 g(64, NB, 12);
        k_proj<<<g, 64, 0, stream>>>(x, O, proj_w, proj_b, x1);
    }
    // ---- ffn branch ----
    {
        dim3 g(64, 24, NB);
        k_ln_conv<<<g, 64, 0, stream>>>(x1, n2w, n2b, fi_w, fi_b, f_pre, 192);
    }
    {
        int total = NB * 192 * NPIX;
        k_dw3<<<(total + 255) / 256, 256, 0, stream>>>(f_pre, fdw_w, fdw_b, f, 192);
    }
    {
        int total = NB * 96 * NPIX;
        k_gate<<<(total + 255) / 256, 256, 0, stream>>>(f, y);
    }
    {
        dim3 g(64, NB, 12);
        k_fo<<<g, 64, 0, stream>>>(x1, y, fo_w, fo_b, (float*)d_out);
    }
}

// Round 4
// 233.894 us; speedup vs baseline: 1.0818x; 1.0818x over previous
//
#include <hip/hip_runtime.h>
#include <hip/hip_bf16.h>
#include <math.h>

#define NPIX 4096   // 64*64
#define DIMC 48
#define NB 2

typedef __attribute__((ext_vector_type(8))) short short8;
typedef __attribute__((ext_vector_type(4))) float floatx4;

static __device__ inline short f2bf(float f) {
    union { float f; unsigned u; } v; v.f = f;
    unsigned r = (v.u + 0x7FFFu + ((v.u >> 16) & 1u)) >> 16;
    return (short)r;
}

// ================= K1: LN1 + qkv 1x1 + dw3x3 + l2norm/temp + bf16 pack ==========
// Tile: interior 8x2 px, halo 10x4 = 40 px. grid (8,32,NB), block 256.
// Qbf,Kbf: [bh][4096][32] row-major (d 24->32 zero-pad). Vbf: [bh][32][4096].
__global__ __launch_bounds__(256) void k_attnpre(
    const float* __restrict__ x, const float* __restrict__ lw, const float* __restrict__ lb,
    const float* __restrict__ cw, const float* __restrict__ cb,
    const float* __restrict__ dww, const float* __restrict__ dwb,
    const float* __restrict__ temp,
    short* __restrict__ Qbf, short* __restrict__ Kbf, short* __restrict__ Vbf)
{
    int ox = blockIdx.x * 8, oy = blockIdx.y * 2, b = blockIdx.z;
    int t = threadIdx.x;
    __shared__ float xn[40][49];     // LN output, halo px
    __shared__ float qp[40][145];    // conv1x1 output (qkv_pre), halo px
    __shared__ float q2[16][145];    // dw3 output, interior px

    // Phase A: LayerNorm per halo pixel
    if (t < 40) {
        int gx = ox + (t % 10) - 1, gy = oy + (t / 10) - 1;
        if ((unsigned)gx < 64u && (unsigned)gy < 64u) {
            int p = gy * 64 + gx;
            const float* xb = x + (size_t)b * DIMC * NPIX;
            float v[48]; float mu = 0.f;
#pragma unroll
            for (int c = 0; c < 48; c++) { v[c] = xb[c * NPIX + p]; mu += v[c]; }
            mu *= (1.f / 48.f);
            float var = 0.f;
#pragma unroll
            for (int c = 0; c < 48; c++) { float d = v[c] - mu; var += d * d; }
            var *= (1.f / 48.f);
            float rs = rsqrtf(var + 1e-5f);
#pragma unroll
            for (int c = 0; c < 48; c++) xn[t][c] = (v[c] - mu) * rs * lw[c] + lb[c];
        }
    }
    __syncthreads();
    // Phase B: 1x1 conv 48->144 for halo px (OOB px -> 0 = spatial zero-pad for dw3)
    {
        int px = t & 63, g = t >> 6;     // g wave-uniform -> scalar weight loads
        if (px < 40) {
            int gx = ox + (px % 10) - 1, gy = oy + (px / 10) - 1;
            bool valid = (unsigned)gx < 64u && (unsigned)gy < 64u;
            float v[48];
#pragma unroll
            for (int c = 0; c < 48; c++) v[c] = xn[px][c];
            for (int o = g * 36; o < g * 36 + 36; o++) {
                float acc = cb[o];
                const float* wr = cw + (size_t)o * 48;
#pragma unroll
                for (int c = 0; c < 48; c++) acc += wr[c] * v[c];
                qp[px][o] = valid ? acc : 0.f;
            }
        }
    }
    __syncthreads();
    // Phase C: depthwise 3x3 at interior px
    for (int task = t; task < 16 * 144; task += 256) {
        int c = task % 144, px = task / 144;
        int hr = (px >> 3) * 10 + (px & 7) + 11;   // (iy+1)*10 + (ix+1)
        const float* wp = dww + (size_t)c * 9;
        float acc = dwb[c];
        acc += qp[hr - 11][c] * wp[0] + qp[hr - 10][c] * wp[1] + qp[hr - 9][c] * wp[2]
             + qp[hr - 1][c]  * wp[3] + qp[hr][c]      * wp[4] + qp[hr + 1][c] * wp[5]
             + qp[hr + 9][c]  * wp[6] + qp[hr + 10][c] * wp[7] + qp[hr + 11][c] * wp[8];
        q2[px][c] = acc;
    }
    __syncthreads();
    // Phase D: l2norm q,k (fold temperature), pack bf16 MFMA layouts
    if (t < 32) {
        int px = t & 15, h = t >> 4;
        int ix = px & 7, iy = px >> 3;
        int n = (oy + iy) * 64 + ox + ix;
        int bh = b * 2 + h;
        float q[24], k[24], vv[24]; float sq = 0.f, sk = 0.f;
#pragma unroll
        for (int c = 0; c < 24; c++) {
            q[c] = q2[px][h * 24 + c];       sq += q[c] * q[c];
            k[c] = q2[px][48 + h * 24 + c];  sk += k[c] * k[c];
            vv[c] = q2[px][96 + h * 24 + c];
        }
        float rq = temp[h] / fmaxf(sqrtf(sq), 1e-12f);
        float rk = 1.f / fmaxf(sqrtf(sk), 1e-12f);
        short qs[32], ks[32];
#pragma unroll
        for (int c = 0; c < 24; c++) { qs[c] = f2bf(q[c] * rq); ks[c] = f2bf(k[c] * rk); }
#pragma unroll
        for (int c = 24; c < 32; c++) { qs[c] = 0; ks[c] = 0; }
        size_t ro = ((size_t)bh * NPIX + n) * 32;
#pragma unroll
        for (int i = 0; i < 4; i++) {
            short8 a, bb;
#pragma unroll
            for (int j = 0; j < 8; j++) { a[j] = qs[i * 8 + j]; bb[j] = ks[i * 8 + j]; }
            *(short8*)(Qbf + ro + i * 8) = a;
            *(short8*)(Kbf + ro + i * 8) = bb;
        }
#pragma unroll
        for (int c = 0; c < 24; c++)
            Vbf[((size_t)bh * 32 + c) * NPIX + n] = f2bf(vv[c]);
#pragma unroll
        for (int c = 24; c < 32; c++)
            Vbf[((size_t)bh * 32 + c) * NPIX + n] = 0;
    }
}

// ================= K2: MFMA flash attention, key-split x4 (round-2 verbatim) =====
// grid: (qt=64, split=4, bh=4), block 256 (wave w owns q-rows qt*64+w*16..+15)
__global__ __launch_bounds__(256) void k_attn_mfma(const short* __restrict__ Qbf,
                                                   const short* __restrict__ Kbf,
                                                   const short* __restrict__ Vbf,
                                                   float* __restrict__ Opart,
                                                   float* __restrict__ lpart) {
    int qt = blockIdx.x;
    int s  = blockIdx.y;
    int bh = blockIdx.z;
    int t = threadIdx.x;
    int w = t >> 6;
    int lane = t & 63;
    int l15 = lane & 15;
    int quad = lane >> 4;

    __shared__ float P[4][16][36];   // per-wave P tile, stride 36 (16B-aligned rows)

    int qrow0 = qt * 64 + w * 16;
    const short* qptr = Qbf + ((size_t)(bh * NPIX + qrow0 + l15)) * 32 + quad * 8;
    short8 aq = *(const short8*)qptr;

    floatx4 zf = {0.f, 0.f, 0.f, 0.f};
    floatx4 o0 = zf, o1 = zf;
    float ls[4] = {0.f, 0.f, 0.f, 0.f};

    int key0 = s * 1024;
    for (int kt = 0; kt < 32; kt++) {
        int kb = key0 + kt * 32;
        const short* kp0 = Kbf + ((size_t)(bh * NPIX + kb + l15)) * 32 + quad * 8;
        short8 b0 = *(const short8*)kp0;
        short8 b1 = *(const short8*)(kp0 + 16 * 32);
        floatx4 s0 = __builtin_amdgcn_mfma_f32_16x16x32_bf16(aq, b0, zf, 0, 0, 0);
        floatx4 s1 = __builtin_amdgcn_mfma_f32_16x16x32_bf16(aq, b1, zf, 0, 0, 0);
#pragma unroll
        for (int r = 0; r < 4; r++) {
            float p0 = __expf(s0[r]);
            float p1 = __expf(s1[r]);
            ls[r] += p0 + p1;
            P[w][quad * 4 + r][l15]      = p0;
            P[w][quad * 4 + r][16 + l15] = p1;
        }
        short8 ap;
#pragma unroll
        for (int j = 0; j < 8; j++) ap[j] = f2bf(P[w][l15][quad * 8 + j]);
        const short* vp0 = Vbf + ((size_t)(bh * 32 + l15)) * NPIX + kb + quad * 8;
        short8 vb0 = *(const short8*)vp0;
        short8 vb1 = *(const short8*)(vp0 + 16 * NPIX);
        o0 = __builtin_amdgcn_mfma_f32_16x16x32_bf16(ap, vb0, o0, 0, 0, 0);
        o1 = __builtin_amdgcn_mfma_f32_16x16x32_bf16(ap, vb1, o1, 0, 0, 0);
    }
#pragma unroll
    for (int m = 1; m < 16; m <<= 1) {
#pragma unroll
        for (int r = 0; r < 4; r++) ls[r] += __shfl_xor(ls[r], m, 64);
    }
#pragma unroll
    for (int r = 0; r < 4; r++) {
        int n = qrow0 + quad * 4 + r;
        size_t oi = (((size_t)(bh * 4 + s) * NPIX) + n) * 32;
        Opart[oi + l15] = o0[r];
        Opart[oi + 16 + l15] = o1[r];
        if (l15 == 0) lpart[((size_t)(bh * 4 + s)) * NPIX + n] = ls[r];
    }
}

// ================= K3: combine splits + normalize + 1x1 proj + residual =========
// grid (128, NB), block 256: 32 px x 8 o-groups (6 oc each)
__global__ __launch_bounds__(256) void k_projred(
    const float* __restrict__ x, const float* __restrict__ Opart,
    const float* __restrict__ lpart,
    const float* __restrict__ w, const float* __restrict__ bias,
    float* __restrict__ x1)
{
    int px = blockIdx.x * 32 + (threadIdx.x & 31);
    int g = threadIdx.x >> 5;    // 0..7
    int b = blockIdx.y;
    float vc[48];
#pragma unroll
    for (int h = 0; h < 2; h++) {
        int bh = b * 2 + h;
        float l = 0.f;
#pragma unroll
        for (int s = 0; s < 4; s++) l += lpart[((size_t)(bh * 4 + s)) * NPIX + px];
        float rl = 1.f / l;
#pragma unroll
        for (int c = 0; c < 24; c++) {
            float acc = 0.f;
#pragma unroll
            for (int s = 0; s < 4; s++)
                acc += Opart[(((size_t)(bh * 4 + s)) * NPIX + px) * 32 + c];
            vc[h * 24 + c] = acc * rl;
        }
    }
#pragma unroll
    for (int j = 0; j < 6; j++) {
        int o = g * 6 + j;
        float acc = bias[o];
        const float* wr = w + (size_t)o * 48;
#pragma unroll
        for (int c = 0; c < 48; c++) acc += wr[c] * vc[c];
        size_t idx = ((size_t)b * 48 + o) * NPIX + px;
        x1[idx] = x[idx] + acc;
    }
}

// ================= K4: LN2 + fi 1x1 + dw3 + GELU-gate + fo 1x1 + residual =======
// Tile: interior 8x2 px, halo 10x4 = 40 px. grid (8,32,NB), block 512.
__global__ __launch_bounds__(512) void k_ffn(
    const float* __restrict__ x1, const float* __restrict__ lw, const float* __restrict__ lb,
    const float* __restrict__ fiw, const float* __restrict__ fib,
    const float* __restrict__ fdww, const float* __restrict__ fdwb,
    const float* __restrict__ fow, const float* __restrict__ fob,
    float* __restrict__ out)
{
    int ox = blockIdx.x * 8, oy = blockIdx.y * 2, b = blockIdx.z;
    int t = threadIdx.x;
    __shared__ float xn[40][49];
    __shared__ float fp[40][193];
    __shared__ float yv[16][97];

    if (t < 40) {
        int gx = ox + (t % 10) - 1, gy = oy + (t / 10) - 1;
        if ((unsigned)gx < 64u && (unsigned)gy < 64u) {
            int p = gy * 64 + gx;
            const float* xb = x1 + (size_t)b * DIMC * NPIX;
            float v[48]; float mu = 0.f;
#pragma unroll
            for (int c = 0; c < 48; c++) { v[c] = xb[c * NPIX + p]; mu += v[c]; }
            mu *= (1.f / 48.f);
            float var = 0.f;
#pragma unroll
            for (int c = 0; c < 48; c++) { float d = v[c] - mu; var += d * d; }
            var *= (1.f / 48.f);
            float rs = rsqrtf(var + 1e-5f);
#pragma unroll
            for (int c = 0; c < 48; c++) xn[t][c] = (v[c] - mu) * rs * lw[c] + lb[c];
        }
    }
    __syncthreads();
    {
        int px = t & 63, g = t >> 6;     // 8 wave-uniform groups of 24 oc
        if (px < 40) {
            int gx = ox + (px % 10) - 1, gy = oy + (px / 10) - 1;
            bool valid = (unsigned)gx < 64u && (unsigned)gy < 64u;
            float v[48];
#pragma unroll
            for (int c = 0; c < 48; c++) v[c] = xn[px][c];
            for (int o = g * 24; o < g * 24 + 24; o++) {
                float acc = fib[o];
                const float* wr = fiw + (size_t)o * 48;
#pragma unroll
                for (int c = 0; c < 48; c++) acc += wr[c] * v[c];
                fp[px][o] = valid ? acc : 0.f;
            }
        }
    }
    __syncthreads();
    // dw3 on both halves + exact GELU gate
    for (int task = t; task < 16 * 96; task += 512) {
        int c = task % 96, px = task / 96;
        int hr = (px >> 3) * 10 + (px & 7) + 11;
        const float* wp = fdww + (size_t)c * 9;
        float a = fdwb[c];
        a += fp[hr - 11][c] * wp[0] + fp[hr - 10][c] * wp[1] + fp[hr - 9][c] * wp[2]
           + fp[hr - 1][c]  * wp[3] + fp[hr][c]      * wp[4] + fp[hr + 1][c] * wp[5]
           + fp[hr + 9][c]  * wp[6] + fp[hr + 10][c] * wp[7] + fp[hr + 11][c] * wp[8];
        int c2 = c + 96;
        const float* wp2 = fdww + (size_t)c2 * 9;
        float g2 = fdwb[c2];
        g2 += fp[hr - 11][c2] * wp2[0] + fp[hr - 10][c2] * wp2[1] + fp[hr - 9][c2] * wp2[2]
            + fp[hr - 1][c2]  * wp2[3] + fp[hr][c2]      * wp2[4] + fp[hr + 1][c2] * wp2[5]
            + fp[hr + 9][c2]  * wp2[6] + fp[hr + 10][c2] * wp2[7] + fp[hr + 11][c2] * wp2[8];
        float ge = 0.5f * a * (1.f + erff(a * 0.70710678118654752f));
        yv[px][c] = ge * g2;
    }
    __syncthreads();
    // fo 1x1 96->48 + residual
    for (int task = t; task < 16 * 48; task += 512) {
        int px = task & 15, o = task >> 4;
        float acc = fob[o];
        const float* wr = fow + (size_t)o * 96;
#pragma unroll
        for (int c = 0; c < 96; c++) acc += wr[c] * yv[px][c];
        int ix = px & 7, iy = px >> 3;
        int n = (oy + iy) * 64 + ox + ix;
        size_t idx = ((size_t)b * 48 + o) * NPIX + n;
        out[idx] = x1[idx] + acc;
    }
}

extern "C" void kernel_launch(void* const* d_in, const int* in_sizes, int n_in,
                              void* d_out, int out_size, void* d_ws, size_t ws_size,
                              hipStream_t stream) {
    const float* x       = (const float*)d_in[0];
    const float* n1w     = (const float*)d_in[1];
    const float* n1b     = (const float*)d_in[2];
    const float* qkv_w   = (const float*)d_in[3];
    const float* qkv_b   = (const float*)d_in[4];
    const float* qkvdw_w = (const float*)d_in[5];
    const float* qkvdw_b = (const float*)d_in[6];
    const float* temp    = (const float*)d_in[7];
    const float* proj_w  = (const float*)d_in[8];
    const float* proj_b  = (const float*)d_in[9];
    const float* n2w     = (const float*)d_in[10];
    const float* n2b     = (const float*)d_in[11];
    const float* fi_w    = (const float*)d_in[12];
    const float* fi_b    = (const float*)d_in[13];
    const float* fdw_w   = (const float*)d_in[14];
    const float* fdw_b   = (const float*)d_in[15];
    const float* fo_w    = (const float*)d_in[16];
    const float* fo_b    = (const float*)d_in[17];

    float* ws = (float*)d_ws;
    // workspace (float units)
    short* Qbf   = (short*)ws;                   // 524288 shorts = 262144 f
    short* Kbf   = Qbf + 524288;                 // 524288 shorts
    short* Vbf   = Kbf + 524288;                 // 524288 shorts
    float* Opart = ws + 786432;                  // 2097152 f
    float* lpart = Opart + 2097152;              // 65536 f
    float* x1    = lpart + 65536;                // 393216 f

    {   // LN1 + qkv1x1 + dw3 + heads
        dim3 g(8, 32, NB);
        k_attnpre<<<g, 256, 0, stream>>>(x, n1w, n1b, qkv_w, qkv_b, qkvdw_w, qkvdw_b,
                                         temp, Qbf, Kbf, Vbf);
    }
    {   // attention
        dim3 g(64, 4, 4);
        k_attn_mfma<<<g, 256, 0, stream>>>(Qbf, Kbf, Vbf, Opart, lpart);
    }
    {   // reduce + proj + residual
        dim3 g(128, NB);
        k_projred<<<g, 256, 0, stream>>>(x, Opart, lpart, proj_w, proj_b, x1);
    }
    {   // LN2 + fi + dw3 + gate + fo + residual
        dim3 g(8, 32, NB);
        k_ffn<<<g, 512, 0, stream>>>(x1, n2w, n2b, fi_w, fi_b, fdw_w, fdw_b,
                                     fo_w, fo_b, (float*)d_out);
    }
}

// Round 5
// 193.720 us; speedup vs baseline: 1.3062x; 1.2074x over previous
//
#include <hip/hip_runtime.h>
#include <hip/hip_bf16.h>
#include <math.h>

#define NPIX 4096   // 64*64
#define DIMC 48
#define NB 2

typedef __attribute__((ext_vector_type(8))) short short8;
typedef __attribute__((ext_vector_type(4))) float floatx4;

static __device__ inline short f2bf(float f) {
    union { float f; unsigned u; } v; v.f = f;
    unsigned r = (v.u + 0x7FFFu + ((v.u >> 16) & 1u)) >> 16;
    return (short)r;
}

// ============ K0: prep bf16 B-layout weights (rows padded to 64 k, zeros) ======
// qkvwbf[144][64], fiwbf[192][64], fowbf[48][96]
__global__ void k_prepw(const float* __restrict__ qkvw, const float* __restrict__ fiw,
                        const float* __restrict__ fow,
                        short* __restrict__ qkvwbf, short* __restrict__ fiwbf,
                        short* __restrict__ fowbf) {
    int idx = blockIdx.x * 256 + threadIdx.x;
    if (idx < 144 * 64) {
        int o = idx >> 6, c = idx & 63;
        qkvwbf[idx] = (c < 48) ? f2bf(qkvw[o * 48 + c]) : (short)0;
        return;
    }
    idx -= 144 * 64;
    if (idx < 192 * 64) {
        int o = idx >> 6, c = idx & 63;
        fiwbf[idx] = (c < 48) ? f2bf(fiw[o * 48 + c]) : (short)0;
        return;
    }
    idx -= 192 * 64;
    if (idx < 48 * 96) {
        fowbf[idx] = f2bf(fow[idx]);
    }
}

// ============ K1: LN1 + qkv 1x1 (MFMA) + dw3x3 + l2norm + bf16 pack ============
// Tile: interior 8x2, halo 10x4 = 40 px. grid (8,32,NB), block 256 (4 waves).
// Qbf,Kbf: [bh][4096][32] row-major. Vbf: [bh][32][4096] with keys PERMUTED
// within each 32-block: key r -> pos (r&15)*2 + (r>>4)  (matches P pack order).
__global__ __launch_bounds__(256) void k_attnpre(
    const float* __restrict__ x, const float* __restrict__ lw, const float* __restrict__ lb,
    const short* __restrict__ qkvwbf, const float* __restrict__ cb,
    const float* __restrict__ dww, const float* __restrict__ dwb,
    const float* __restrict__ temp,
    short* __restrict__ Qbf, short* __restrict__ Kbf, short* __restrict__ Vbf)
{
    int ox = blockIdx.x * 8, oy = blockIdx.y * 2, b = blockIdx.z;
    int t = threadIdx.x;
    int w = t >> 6, lane = t & 63, l15 = lane & 15, quad = lane >> 4;

    __shared__ short xnbf[48][72];     // bf16 LN out, rows=halo px (40..47 zero), 16B rows
    __shared__ float fp[48][148];      // conv1x1 out fp32
    __shared__ float q2[16][148];      // dw3 out, interior px

    // Phase A: LayerNorm -> bf16 (A-layout rows)
    if (t < 48) {
        float v[48];
        if (t < 40) {
            int gx = ox + (t % 10) - 1, gy = oy + (t / 10) - 1;
            if ((unsigned)gx < 64u && (unsigned)gy < 64u) {
                int p = gy * 64 + gx;
                const float* xb = x + (size_t)b * DIMC * NPIX;
                float mu = 0.f;
#pragma unroll
                for (int c = 0; c < 48; c++) { v[c] = xb[c * NPIX + p]; mu += v[c]; }
                mu *= (1.f / 48.f);
                float var = 0.f;
#pragma unroll
                for (int c = 0; c < 48; c++) { float d = v[c] - mu; var += d * d; }
                var *= (1.f / 48.f);
                float rs = rsqrtf(var + 1e-5f);
#pragma unroll
                for (int c = 0; c < 48; c++) v[c] = (v[c] - mu) * rs * lw[c] + lb[c];
            } else {
#pragma unroll
                for (int c = 0; c < 48; c++) v[c] = 0.f;
            }
        } else {
#pragma unroll
            for (int c = 0; c < 48; c++) v[c] = 0.f;
        }
        unsigned* row = (unsigned*)&xnbf[t][0];
#pragma unroll
        for (int i = 0; i < 24; i++) {
            __hip_bfloat162 pk = __float22bfloat162_rn(make_float2(v[2 * i], v[2 * i + 1]));
            row[i] = *(unsigned*)&pk;
        }
#pragma unroll
        for (int i = 24; i < 36; i++) row[i] = 0u;
    }
    __syncthreads();
    // Phase B: 1x1 conv 48->144 via MFMA. 3 px-tiles x 9 oc-tiles = 27 jobs.
    floatx4 zf = {0.f, 0.f, 0.f, 0.f};
    for (int job = w; job < 27; job += 4) {
        int pt = job / 9, ot = job % 9;
        short8 a0 = *(const short8*)&xnbf[pt * 16 + l15][quad * 8];
        short8 a1 = *(const short8*)&xnbf[pt * 16 + l15][32 + quad * 8];
        const short* wb = qkvwbf + (ot * 16 + l15) * 64;
        short8 b0 = *(const short8*)(wb + quad * 8);
        short8 b1 = *(const short8*)(wb + 32 + quad * 8);
        floatx4 c = __builtin_amdgcn_mfma_f32_16x16x32_bf16(a0, b0, zf, 0, 0, 0);
        c = __builtin_amdgcn_mfma_f32_16x16x32_bf16(a1, b1, c, 0, 0, 0);
        float bi = cb[ot * 16 + l15];
#pragma unroll
        for (int r = 0; r < 4; r++) {
            int hp = pt * 16 + quad * 4 + r;
            if (hp < 40) {
                int gx = ox + hp % 10 - 1, gy = oy + hp / 10 - 1;
                bool valid = (unsigned)gx < 64u && (unsigned)gy < 64u;
                fp[hp][ot * 16 + l15] = valid ? (c[r] + bi) : 0.f;
            }
        }
    }
    __syncthreads();
    // Phase C: depthwise 3x3 at interior px
    for (int task = t; task < 16 * 144; task += 256) {
        int c = task % 144, px = task / 144;
        int hr = (px >> 3) * 10 + (px & 7) + 11;
        const float* wp = dww + (size_t)c * 9;
        float acc = dwb[c];
        acc += fp[hr - 11][c] * wp[0] + fp[hr - 10][c] * wp[1] + fp[hr - 9][c] * wp[2]
             + fp[hr - 1][c]  * wp[3] + fp[hr][c]      * wp[4] + fp[hr + 1][c] * wp[5]
             + fp[hr + 9][c]  * wp[6] + fp[hr + 10][c] * wp[7] + fp[hr + 11][c] * wp[8];
        q2[px][c] = acc;
    }
    __syncthreads();
    // Phase D: l2norm q,k (fold temperature), pack layouts; V key-permuted
    if (t < 32) {
        int px = t & 15, h = t >> 4;
        int ix = px & 7, iy = px >> 3;
        int n = (oy + iy) * 64 + ox + ix;
        int bh = b * 2 + h;
        float q[24], k[24], vv[24]; float sq = 0.f, sk = 0.f;
#pragma unroll
        for (int c = 0; c < 24; c++) {
            q[c] = q2[px][h * 24 + c];       sq += q[c] * q[c];
            k[c] = q2[px][48 + h * 24 + c];  sk += k[c] * k[c];
            vv[c] = q2[px][96 + h * 24 + c];
        }
        float rq = temp[h] / fmaxf(sqrtf(sq), 1e-12f);
        float rk = 1.f / fmaxf(sqrtf(sk), 1e-12f);
        short qs[32], ks[32];
#pragma unroll
        for (int c = 0; c < 24; c++) { qs[c] = f2bf(q[c] * rq); ks[c] = f2bf(k[c] * rk); }
#pragma unroll
        for (int c = 24; c < 32; c++) { qs[c] = 0; ks[c] = 0; }
        size_t ro = ((size_t)bh * NPIX + n) * 32;
#pragma unroll
        for (int i = 0; i < 4; i++) {
            short8 a, bb;
#pragma unroll
            for (int j = 0; j < 8; j++) { a[j] = qs[i * 8 + j]; bb[j] = ks[i * 8 + j]; }
            *(short8*)(Qbf + ro + i * 8) = a;
            *(short8*)(Kbf + ro + i * 8) = bb;
        }
        int r5 = n & 31;
        int vcol = (n & ~31) + ((r5 & 15) * 2 + (r5 >> 4));   // permuted position
#pragma unroll
        for (int c = 0; c < 24; c++)
            Vbf[((size_t)bh * 32 + c) * NPIX + vcol] = f2bf(vv[c]);
#pragma unroll
        for (int c = 24; c < 32; c++)
            Vbf[((size_t)bh * 32 + c) * NPIX + vcol] = 0;
    }
}

// ============ K2: MFMA flash attention, LDS-staged K/V double buffer ===========
// grid: (qt=64, split=4, bh=4), block 256 (wave w owns q-rows qt*64+w*16..+15;
// all 4 waves share each 32-key K/V tile staged in LDS).
// Opart: [bh][4][32ch][4096] fp32 channel-major; lpart: [bh][4][4096]
__global__ __launch_bounds__(256) void k_attn_mfma(const short* __restrict__ Qbf,
                                                   const short* __restrict__ Kbf,
                                                   const short* __restrict__ Vbf,
                                                   float* __restrict__ Opart,
                                                   float* __restrict__ lpart) {
    int qt = blockIdx.x, s = blockIdx.y, bh = blockIdx.z;
    int t = threadIdx.x;
    int w = t >> 6, lane = t & 63, l15 = lane & 15, quad = lane >> 4;

    __shared__ short tileK[2][32][40];   // rows=key, 16B-aligned, <=2-way banks
    __shared__ short tileV[2][32][40];   // rows=ch, keys in permuted order
    __shared__ short P[4][16][40];       // bf16 P, per-wave

    int qrow0 = qt * 64 + w * 16;
    short8 aq = *(const short8*)(Qbf + ((size_t)bh * NPIX + qrow0 + l15) * 32 + quad * 8);

    // cooperative staging: threads 0..127 -> K tile, 128..255 -> V tile
    int i = t & 127;
    int rr = i >> 2, qh = i & 3;
    bool isV = t >= 128;
    const short* srcK = Kbf + ((size_t)bh * NPIX + rr) * 32 + qh * 8;
    const short* srcV = Vbf + ((size_t)(bh * 32 + rr)) * NPIX + qh * 8;
    int dstoff = rr * 40 + qh * 8;

    int key0 = s * 1024;
    {   // prologue: stage tile 0 into buf 0
        short8 ld = isV ? *(const short8*)(srcV + key0)
                        : *(const short8*)(srcK + (size_t)key0 * 32);
        short* dst = (isV ? &tileV[0][0][0] : &tileK[0][0][0]) + dstoff;
        *(short8*)dst = ld;
    }

    floatx4 zf = {0.f, 0.f, 0.f, 0.f};
    floatx4 o0 = zf, o1 = zf;
    float ls[4] = {0.f, 0.f, 0.f, 0.f};

    for (int kt = 0; kt < 32; kt++) {
        __syncthreads();                 // buf[kt&1] ready; prior reads of buf[1-cur] done
        int cur = kt & 1;
        short8 ld = {};
        if (kt < 31) {
            int kabs = key0 + (kt + 1) * 32;
            ld = isV ? *(const short8*)(srcV + kabs)
                     : *(const short8*)(srcK + (size_t)kabs * 32);
        }
        short8 b0  = *(const short8*)&tileK[cur][l15][quad * 8];
        short8 b1  = *(const short8*)&tileK[cur][l15 + 16][quad * 8];
        short8 vb0 = *(const short8*)&tileV[cur][l15][quad * 8];
        short8 vb1 = *(const short8*)&tileV[cur][l15 + 16][quad * 8];
        floatx4 s0 = __builtin_amdgcn_mfma_f32_16x16x32_bf16(aq, b0, zf, 0, 0, 0);
        floatx4 s1 = __builtin_amdgcn_mfma_f32_16x16x32_bf16(aq, b1, zf, 0, 0, 0);
#pragma unroll
        for (int r = 0; r < 4; r++) {
            float p0 = __expf(s0[r]);    // key kb+l15      -> pos 2*l15
            float p1 = __expf(s1[r]);    // key kb+16+l15   -> pos 2*l15+1
            ls[r] += p0 + p1;
            __hip_bfloat162 pk = __float22bfloat162_rn(make_float2(p0, p1));
            *(unsigned*)&P[w][quad * 4 + r][l15 * 2] = *(unsigned*)&pk;
        }
        short8 ap = *(const short8*)&P[w][l15][quad * 8];
        o0 = __builtin_amdgcn_mfma_f32_16x16x32_bf16(ap, vb0, o0, 0, 0, 0);
        o1 = __builtin_amdgcn_mfma_f32_16x16x32_bf16(ap, vb1, o1, 0, 0, 0);
        if (kt < 31) {
            short* dst = (isV ? &tileV[1 - cur][0][0] : &tileK[1 - cur][0][0]) + dstoff;
            *(short8*)dst = ld;
        }
    }
#pragma unroll
    for (int m = 1; m < 16; m <<= 1) {
#pragma unroll
        for (int r = 0; r < 4; r++) ls[r] += __shfl_xor(ls[r], m, 64);
    }
#pragma unroll
    for (int r = 0; r < 4; r++) {
        int n = qrow0 + quad * 4 + r;
        size_t base = (size_t)(bh * 4 + s) * 32;
        Opart[(base + l15) * NPIX + n] = o0[r];
        Opart[(base + 16 + l15) * NPIX + n] = o1[r];
        if (l15 == 0) lpart[((size_t)(bh * 4 + s)) * NPIX + n] = ls[r];
    }
}

// ============ K3: combine splits + normalize + 1x1 proj + residual =============
// grid (128, NB), block 256: 32 px x 8 o-groups (6 oc each). Opart channel-major.
__global__ __launch_bounds__(256) void k_projred(
    const float* __restrict__ x, const float* __restrict__ Opart,
    const float* __restrict__ lpart,
    const float* __restrict__ w, const float* __restrict__ bias,
    float* __restrict__ x1)
{
    int px = blockIdx.x * 32 + (threadIdx.x & 31);
    int g = threadIdx.x >> 5;    // 0..7
    int b = blockIdx.y;
    float vc[48];
#pragma unroll
    for (int h = 0; h < 2; h++) {
        int bh = b * 2 + h;
        float l = 0.f;
#pragma unroll
        for (int s = 0; s < 4; s++) l += lpart[((size_t)(bh * 4 + s)) * NPIX + px];
        float rl = 1.f / l;
#pragma unroll
        for (int c = 0; c < 24; c++) {
            float acc = 0.f;
#pragma unroll
            for (int s = 0; s < 4; s++)
                acc += Opart[((size_t)(bh * 4 + s) * 32 + c) * NPIX + px];
            vc[h * 24 + c] = acc * rl;
        }
    }
#pragma unroll
    for (int j = 0; j < 6; j++) {
        int o = g * 6 + j;
        float acc = bias[o];
        const float* wr = w + (size_t)o * 48;
#pragma unroll
        for (int c = 0; c < 48; c++) acc += wr[c] * vc[c];
        size_t idx = ((size_t)b * 48 + o) * NPIX + px;
        x1[idx] = x[idx] + acc;
    }
}

// ============ K4: LN2 + fi 1x1 (MFMA) + dw3 + GELU-gate + fo 1x1 (MFMA) + res ==
// Tile: interior 8x2, halo 10x4 = 40 px. grid (8,32,NB), block 256 (4 waves).
__global__ __launch_bounds__(256) void k_ffn(
    const float* __restrict__ x1, const float* __restrict__ lw, const float* __restrict__ lb,
    const short* __restrict__ fiwbf, const float* __restrict__ fib,
    const float* __restrict__ fdww, const float* __restrict__ fdwb,
    const short* __restrict__ fowbf, const float* __restrict__ fob,
    float* __restrict__ out)
{
    int ox = blockIdx.x * 8, oy = blockIdx.y * 2, b = blockIdx.z;
    int t = threadIdx.x;
    int w = t >> 6, lane = t & 63, l15 = lane & 15, quad = lane >> 4;

    __shared__ short xnbf[48][72];
    __shared__ float fp[48][196];
    __shared__ short yv[16][104];

    // Phase A: LN -> bf16
    if (t < 48) {
        float v[48];
        if (t < 40) {
            int gx = ox + (t % 10) - 1, gy = oy + (t / 10) - 1;
            if ((unsigned)gx < 64u && (unsigned)gy < 64u) {
                int p = gy * 64 + gx;
                const float* xb = x1 + (size_t)b * DIMC * NPIX;
                float mu = 0.f;
#pragma unroll
                for (int c = 0; c < 48; c++) { v[c] = xb[c * NPIX + p]; mu += v[c]; }
                mu *= (1.f / 48.f);
                float var = 0.f;
#pragma unroll
                for (int c = 0; c < 48; c++) { float d = v[c] - mu; var += d * d; }
                var *= (1.f / 48.f);
                float rs = rsqrtf(var + 1e-5f);
#pragma unroll
                for (int c = 0; c < 48; c++) v[c] = (v[c] - mu) * rs * lw[c] + lb[c];
            } else {
#pragma unroll
                for (int c = 0; c < 48; c++) v[c] = 0.f;
            }
        } else {
#pragma unroll
            for (int c = 0; c < 48; c++) v[c] = 0.f;
        }
        unsigned* row = (unsigned*)&xnbf[t][0];
#pragma unroll
        for (int i = 0; i < 24; i++) {
            __hip_bfloat162 pk = __float22bfloat162_rn(make_float2(v[2 * i], v[2 * i + 1]));
            row[i] = *(unsigned*)&pk;
        }
#pragma unroll
        for (int i = 24; i < 36; i++) row[i] = 0u;
    }
    __syncthreads();
    // Phase B: fi conv 48->192 via MFMA: 3 px-tiles x 12 oc-tiles = 36 jobs
    floatx4 zf = {0.f, 0.f, 0.f, 0.f};
    for (int job = w; job < 36; job += 4) {
        int pt = job / 12, ot = job % 12;
        short8 a0 = *(const short8*)&xnbf[pt * 16 + l15][quad * 8];
        short8 a1 = *(const short8*)&xnbf[pt * 16 + l15][32 + quad * 8];
        const short* wb = fiwbf + (ot * 16 + l15) * 64;
        short8 b0 = *(const short8*)(wb + quad * 8);
        short8 b1 = *(const short8*)(wb + 32 + quad * 8);
        floatx4 c = __builtin_amdgcn_mfma_f32_16x16x32_bf16(a0, b0, zf, 0, 0, 0);
        c = __builtin_amdgcn_mfma_f32_16x16x32_bf16(a1, b1, c, 0, 0, 0);
        float bi = fib[ot * 16 + l15];
#pragma unroll
        for (int r = 0; r < 4; r++) {
            int hp = pt * 16 + quad * 4 + r;
            if (hp < 40) {
                int gx = ox + hp % 10 - 1, gy = oy + hp / 10 - 1;
                bool valid = (unsigned)gx < 64u && (unsigned)gy < 64u;
                fp[hp][ot * 16 + l15] = valid ? (c[r] + bi) : 0.f;
            }
        }
    }
    __syncthreads();
    // Phase C: dw3 both halves + exact GELU gate -> yv (bf16 A-layout)
    for (int task = t; task < 16 * 96; task += 256) {
        int c = task % 96, px = task / 96;
        int hr = (px >> 3) * 10 + (px & 7) + 11;
        const float* wp = fdww + (size_t)c * 9;
        float a = fdwb[c];
        a += fp[hr - 11][c] * wp[0] + fp[hr - 10][c] * wp[1] + fp[hr - 9][c] * wp[2]
           + fp[hr - 1][c]  * wp[3] + fp[hr][c]      * wp[4] + fp[hr + 1][c] * wp[5]
           + fp[hr + 9][c]  * wp[6] + fp[hr + 10][c] * wp[7] + fp[hr + 11][c] * wp[8];
        int c2 = c + 96;
        const float* wp2 = fdww + (size_t)c2 * 9;
        float g2 = fdwb[c2];
        g2 += fp[hr - 11][c2] * wp2[0] + fp[hr - 10][c2] * wp2[1] + fp[hr - 9][c2] * wp2[2]
            + fp[hr - 1][c2]  * wp2[3] + fp[hr][c2]      * wp2[4] + fp[hr + 1][c2] * wp2[5]
            + fp[hr + 9][c2]  * wp2[6] + fp[hr + 10][c2] * wp2[7] + fp[hr + 11][c2] * wp2[8];
        float ge = 0.5f * a * (1.f + erff(a * 0.70710678118654752f));
        yv[px][c] = f2bf(ge * g2);
    }
    __syncthreads();
    // Phase D: fo conv 96->48 via MFMA (3 oc-tiles, K=96) + bias + residual
    if (w < 3) {
        int ot = w;
        floatx4 c = zf;
#pragma unroll
        for (int k = 0; k < 3; k++) {
            short8 a = *(const short8*)&yv[l15][k * 32 + quad * 8];
            short8 bb = *(const short8*)(fowbf + (ot * 16 + l15) * 96 + k * 32 + quad * 8);
            c = __builtin_amdgcn_mfma_f32_16x16x32_bf16(a, bb, c, 0, 0, 0);
        }
        int oc = ot * 16 + l15;
        float bi = fob[oc];
#pragma unroll
        for (int r = 0; r < 4; r++) {
            int px = quad * 4 + r;
            int n = (oy + (px >> 3)) * 64 + ox + (px & 7);
            size_t idx = ((size_t)b * 48 + oc) * NPIX + n;
            out[idx] = x1[idx] + c[r] + bi;
        }
    }
}

extern "C" void kernel_launch(void* const* d_in, const int* in_sizes, int n_in,
                              void* d_out, int out_size, void* d_ws, size_t ws_size,
                              hipStream_t stream) {
    const float* x       = (const float*)d_in[0];
    const float* n1w     = (const float*)d_in[1];
    const float* n1b     = (const float*)d_in[2];
    const float* qkv_w   = (const float*)d_in[3];
    const float* qkv_b   = (const float*)d_in[4];
    const float* qkvdw_w = (const float*)d_in[5];
    const float* qkvdw_b = (const float*)d_in[6];
    const float* temp    = (const float*)d_in[7];
    const float* proj_w  = (const float*)d_in[8];
    const float* proj_b  = (const float*)d_in[9];
    const float* n2w     = (const float*)d_in[10];
    const float* n2b     = (const float*)d_in[11];
    const float* fi_w    = (const float*)d_in[12];
    const float* fi_b    = (const float*)d_in[13];
    const float* fdw_w   = (const float*)d_in[14];
    const float* fdw_b   = (const float*)d_in[15];
    const float* fo_w    = (const float*)d_in[16];
    const float* fo_b    = (const float*)d_in[17];

    float* ws = (float*)d_ws;
    short* Qbf   = (short*)ws;                   // 524288 shorts
    short* Kbf   = Qbf + 524288;                 // 524288 shorts
    short* Vbf   = Kbf + 524288;                 // 524288 shorts (= 786432 floats total)
    float* Opart = ws + 786432;                  // 2097152 f
    float* lpart = Opart + 2097152;              // 65536 f
    float* x1    = lpart + 65536;                // 393216 f
    short* qkvwbf = (short*)(x1 + 393216);       // 9216 shorts
    short* fiwbf  = qkvwbf + 9216;               // 12288 shorts
    short* fowbf  = fiwbf + 12288;               // 4608 shorts

    {   // weights -> bf16 B-layout
        int total = 144 * 64 + 192 * 64 + 48 * 96;
        k_prepw<<<(total + 255) / 256, 256, 0, stream>>>(qkv_w, fi_w, fo_w,
                                                         qkvwbf, fiwbf, fowbf);
    }
    {   // LN1 + qkv1x1(MFMA) + dw3 + heads
        dim3 g(8, 32, NB);
        k_attnpre<<<g, 256, 0, stream>>>(x, n1w, n1b, qkvwbf, qkv_b, qkvdw_w, qkvdw_b,
                                         temp, Qbf, Kbf, Vbf);
    }
    {   // attention
        dim3 g(64, 4, 4);
        k_attn_mfma<<<g, 256, 0, stream>>>(Qbf, Kbf, Vbf, Opart, lpart);
    }
    {   // reduce + proj + residual
        dim3 g(128, NB);
        k_projred<<<g, 256, 0, stream>>>(x, Opart, lpart, proj_w, proj_b, x1);
    }
    {   // LN2 + fi(MFMA) + dw3 + gate + fo(MFMA) + residual
        dim3 g(8, 32, NB);
        k_ffn<<<g, 256, 0, stream>>>(x1, n2w, n2b, fiwbf, fi_b, fdw_w, fdw_b,
                                     fowbf, fo_b, (float*)d_out);
    }
}

// Round 6
// 158.494 us; speedup vs baseline: 1.5965x; 1.2223x over previous
//
#include <hip/hip_runtime.h>
#include <hip/hip_bf16.h>
#include <math.h>

#define NPIX 4096   // 64*64
#define DIMC 48
#define NB 2
#define SPLIT 8

typedef __attribute__((ext_vector_type(8))) short short8;
typedef __attribute__((ext_vector_type(4))) float floatx4;

static __device__ inline short f2bf(float f) {
    union { float f; unsigned u; } v; v.f = f;
    unsigned r = (v.u + 0x7FFFu + ((v.u >> 16) & 1u)) >> 16;
    return (short)r;
}

// ============ K0: prep bf16 B-layout weights (rows padded to 64 k, zeros) ======
// qkvwbf[144][64], fiwbf[192][64], fowbf[48][96], projwbf[48][64]
__global__ void k_prepw(const float* __restrict__ qkvw, const float* __restrict__ fiw,
                        const float* __restrict__ fow, const float* __restrict__ projw,
                        short* __restrict__ qkvwbf, short* __restrict__ fiwbf,
                        short* __restrict__ fowbf, short* __restrict__ projwbf) {
    int idx = blockIdx.x * 256 + threadIdx.x;
    if (idx < 144 * 64) {
        int o = idx >> 6, c = idx & 63;
        qkvwbf[idx] = (c < 48) ? f2bf(qkvw[o * 48 + c]) : (short)0;
        return;
    }
    idx -= 144 * 64;
    if (idx < 192 * 64) {
        int o = idx >> 6, c = idx & 63;
        fiwbf[idx] = (c < 48) ? f2bf(fiw[o * 48 + c]) : (short)0;
        return;
    }
    idx -= 192 * 64;
    if (idx < 48 * 96) {
        fowbf[idx] = f2bf(fow[idx]);
        return;
    }
    idx -= 48 * 96;
    if (idx < 48 * 64) {
        int o = idx >> 6, c = idx & 63;
        projwbf[idx] = (c < 48) ? f2bf(projw[o * 48 + c]) : (short)0;
    }
}

// ============ K1: LN1 + qkv 1x1 (MFMA) + dw3x3 + l2norm + bf16 pack ============
// Tile: interior 8x2, halo 10x4 = 40 px. grid (8,32,NB), block 256 (4 waves).
// Qbf,Kbf: [bh][4096][32] row-major. Vbf: [bh][32][4096] with keys PERMUTED
// within each 32-block: key r -> pos (r&15)*2 + (r>>4)  (matches P pack order).
__global__ __launch_bounds__(256) void k_attnpre(
    const float* __restrict__ x, const float* __restrict__ lw, const float* __restrict__ lb,
    const short* __restrict__ qkvwbf, const float* __restrict__ cb,
    const float* __restrict__ dww, const float* __restrict__ dwb,
    const float* __restrict__ temp,
    short* __restrict__ Qbf, short* __restrict__ Kbf, short* __restrict__ Vbf)
{
    int ox = blockIdx.x * 8, oy = blockIdx.y * 2, b = blockIdx.z;
    int t = threadIdx.x;
    int w = t >> 6, lane = t & 63, l15 = lane & 15, quad = lane >> 4;

    __shared__ short xnbf[48][72];     // bf16 LN out, rows=halo px (40..47 zero)
    __shared__ float fp[48][148];      // conv1x1 out fp32
    __shared__ float q2[16][148];      // dw3 out, interior px

    // Phase A: LayerNorm -> bf16 (A-layout rows)
    if (t < 48) {
        float v[48];
        if (t < 40) {
            int gx = ox + (t % 10) - 1, gy = oy + (t / 10) - 1;
            if ((unsigned)gx < 64u && (unsigned)gy < 64u) {
                int p = gy * 64 + gx;
                const float* xb = x + (size_t)b * DIMC * NPIX;
                float mu = 0.f;
#pragma unroll
                for (int c = 0; c < 48; c++) { v[c] = xb[c * NPIX + p]; mu += v[c]; }
                mu *= (1.f / 48.f);
                float var = 0.f;
#pragma unroll
                for (int c = 0; c < 48; c++) { float d = v[c] - mu; var += d * d; }
                var *= (1.f / 48.f);
                float rs = rsqrtf(var + 1e-5f);
#pragma unroll
                for (int c = 0; c < 48; c++) v[c] = (v[c] - mu) * rs * lw[c] + lb[c];
            } else {
#pragma unroll
                for (int c = 0; c < 48; c++) v[c] = 0.f;
            }
        } else {
#pragma unroll
            for (int c = 0; c < 48; c++) v[c] = 0.f;
        }
        unsigned* row = (unsigned*)&xnbf[t][0];
#pragma unroll
        for (int i = 0; i < 24; i++) {
            __hip_bfloat162 pk = __float22bfloat162_rn(make_float2(v[2 * i], v[2 * i + 1]));
            row[i] = *(unsigned*)&pk;
        }
#pragma unroll
        for (int i = 24; i < 36; i++) row[i] = 0u;
    }
    __syncthreads();
    // Phase B: 1x1 conv 48->144 via MFMA. 3 px-tiles x 9 oc-tiles = 27 jobs.
    floatx4 zf = {0.f, 0.f, 0.f, 0.f};
    for (int job = w; job < 27; job += 4) {
        int pt = job / 9, ot = job % 9;
        short8 a0 = *(const short8*)&xnbf[pt * 16 + l15][quad * 8];
        short8 a1 = *(const short8*)&xnbf[pt * 16 + l15][32 + quad * 8];
        const short* wb = qkvwbf + (ot * 16 + l15) * 64;
        short8 b0 = *(const short8*)(wb + quad * 8);
        short8 b1 = *(const short8*)(wb + 32 + quad * 8);
        floatx4 c = __builtin_amdgcn_mfma_f32_16x16x32_bf16(a0, b0, zf, 0, 0, 0);
        c = __builtin_amdgcn_mfma_f32_16x16x32_bf16(a1, b1, c, 0, 0, 0);
        float bi = cb[ot * 16 + l15];
#pragma unroll
        for (int r = 0; r < 4; r++) {
            int hp = pt * 16 + quad * 4 + r;
            if (hp < 40) {
                int gx = ox + hp % 10 - 1, gy = oy + hp / 10 - 1;
                bool valid = (unsigned)gx < 64u && (unsigned)gy < 64u;
                fp[hp][ot * 16 + l15] = valid ? (c[r] + bi) : 0.f;
            }
        }
    }
    __syncthreads();
    // Phase C: depthwise 3x3 at interior px
    for (int task = t; task < 16 * 144; task += 256) {
        int c = task % 144, px = task / 144;
        int hr = (px >> 3) * 10 + (px & 7) + 11;
        const float* wp = dww + (size_t)c * 9;
        float acc = dwb[c];
        acc += fp[hr - 11][c] * wp[0] + fp[hr - 10][c] * wp[1] + fp[hr - 9][c] * wp[2]
             + fp[hr - 1][c]  * wp[3] + fp[hr][c]      * wp[4] + fp[hr + 1][c] * wp[5]
             + fp[hr + 9][c]  * wp[6] + fp[hr + 10][c] * wp[7] + fp[hr + 11][c] * wp[8];
        q2[px][c] = acc;
    }
    __syncthreads();
    // Phase D: l2norm q,k (fold temperature), pack layouts; V key-permuted
    if (t < 32) {
        int px = t & 15, h = t >> 4;
        int ix = px & 7, iy = px >> 3;
        int n = (oy + iy) * 64 + ox + ix;
        int bh = b * 2 + h;
        float q[24], k[24], vv[24]; float sq = 0.f, sk = 0.f;
#pragma unroll
        for (int c = 0; c < 24; c++) {
            q[c] = q2[px][h * 24 + c];       sq += q[c] * q[c];
            k[c] = q2[px][48 + h * 24 + c];  sk += k[c] * k[c];
            vv[c] = q2[px][96 + h * 24 + c];
        }
        float rq = temp[h] / fmaxf(sqrtf(sq), 1e-12f);
        float rk = 1.f / fmaxf(sqrtf(sk), 1e-12f);
        short qs[32], ks[32];
#pragma unroll
        for (int c = 0; c < 24; c++) { qs[c] = f2bf(q[c] * rq); ks[c] = f2bf(k[c] * rk); }
#pragma unroll
        for (int c = 24; c < 32; c++) { qs[c] = 0; ks[c] = 0; }
        size_t ro = ((size_t)bh * NPIX + n) * 32;
#pragma unroll
        for (int i = 0; i < 4; i++) {
            short8 a, bb;
#pragma unroll
            for (int j = 0; j < 8; j++) { a[j] = qs[i * 8 + j]; bb[j] = ks[i * 8 + j]; }
            *(short8*)(Qbf + ro + i * 8) = a;
            *(short8*)(Kbf + ro + i * 8) = bb;
        }
        int r5 = n & 31;
        int vcol = (n & ~31) + ((r5 & 15) * 2 + (r5 >> 4));   // permuted position
#pragma unroll
        for (int c = 0; c < 24; c++)
            Vbf[((size_t)bh * 32 + c) * NPIX + vcol] = f2bf(vv[c]);
#pragma unroll
        for (int c = 24; c < 32; c++)
            Vbf[((size_t)bh * 32 + c) * NPIX + vcol] = 0;
    }
}

// ============ K2: MFMA flash attention, LDS-staged K/V double buffer ===========
// grid: (qt=64, split=8, bh=4), block 256 (wave w owns q-rows qt*64+w*16..+15;
// all 4 waves share each 32-key K/V tile staged in LDS).
// Opart: [bh][SPLIT][32ch][4096] fp32 channel-major; lpart: [bh][SPLIT][4096]
__global__ __launch_bounds__(256) void k_attn_mfma(const short* __restrict__ Qbf,
                                                   const short* __restrict__ Kbf,
                                                   const short* __restrict__ Vbf,
                                                   float* __restrict__ Opart,
                                                   float* __restrict__ lpart) {
    int qt = blockIdx.x, s = blockIdx.y, bh = blockIdx.z;
    int t = threadIdx.x;
    int w = t >> 6, lane = t & 63, l15 = lane & 15, quad = lane >> 4;

    __shared__ short tileK[2][32][40];
    __shared__ short tileV[2][32][40];
    __shared__ short P[4][16][40];

    int qrow0 = qt * 64 + w * 16;
    short8 aq = *(const short8*)(Qbf + ((size_t)bh * NPIX + qrow0 + l15) * 32 + quad * 8);

    int i = t & 127;
    int rr = i >> 2, qh = i & 3;
    bool isV = t >= 128;
    const short* srcK = Kbf + ((size_t)bh * NPIX + rr) * 32 + qh * 8;
    const short* srcV = Vbf + ((size_t)(bh * 32 + rr)) * NPIX + qh * 8;
    int dstoff = rr * 40 + qh * 8;

    int key0 = s * (NPIX / SPLIT);
    {
        short8 ld = isV ? *(const short8*)(srcV + key0)
                        : *(const short8*)(srcK + (size_t)key0 * 32);
        short* dst = (isV ? &tileV[0][0][0] : &tileK[0][0][0]) + dstoff;
        *(short8*)dst = ld;
    }

    floatx4 zf = {0.f, 0.f, 0.f, 0.f};
    floatx4 o0 = zf, o1 = zf;
    float ls[4] = {0.f, 0.f, 0.f, 0.f};

    const int NKT = (NPIX / SPLIT) / 32;   // 16
    for (int kt = 0; kt < NKT; kt++) {
        __syncthreads();
        int cur = kt & 1;
        short8 ld = {};
        if (kt < NKT - 1) {
            int kabs = key0 + (kt + 1) * 32;
            ld = isV ? *(const short8*)(srcV + kabs)
                     : *(const short8*)(srcK + (size_t)kabs * 32);
        }
        short8 b0  = *(const short8*)&tileK[cur][l15][quad * 8];
        short8 b1  = *(const short8*)&tileK[cur][l15 + 16][quad * 8];
        short8 vb0 = *(const short8*)&tileV[cur][l15][quad * 8];
        short8 vb1 = *(const short8*)&tileV[cur][l15 + 16][quad * 8];
        floatx4 s0 = __builtin_amdgcn_mfma_f32_16x16x32_bf16(aq, b0, zf, 0, 0, 0);
        floatx4 s1 = __builtin_amdgcn_mfma_f32_16x16x32_bf16(aq, b1, zf, 0, 0, 0);
#pragma unroll
        for (int r = 0; r < 4; r++) {
            float p0 = __expf(s0[r]);
            float p1 = __expf(s1[r]);
            ls[r] += p0 + p1;
            __hip_bfloat162 pk = __float22bfloat162_rn(make_float2(p0, p1));
            *(unsigned*)&P[w][quad * 4 + r][l15 * 2] = *(unsigned*)&pk;
        }
        short8 ap = *(const short8*)&P[w][l15][quad * 8];
        o0 = __builtin_amdgcn_mfma_f32_16x16x32_bf16(ap, vb0, o0, 0, 0, 0);
        o1 = __builtin_amdgcn_mfma_f32_16x16x32_bf16(ap, vb1, o1, 0, 0, 0);
        if (kt < NKT - 1) {
            short* dst = (isV ? &tileV[1 - cur][0][0] : &tileK[1 - cur][0][0]) + dstoff;
            *(short8*)dst = ld;
        }
    }
#pragma unroll
    for (int m = 1; m < 16; m <<= 1) {
#pragma unroll
        for (int r = 0; r < 4; r++) ls[r] += __shfl_xor(ls[r], m, 64);
    }
#pragma unroll
    for (int r = 0; r < 4; r++) {
        int n = qrow0 + quad * 4 + r;
        size_t base = (size_t)(bh * SPLIT + s) * 32;
        Opart[(base + l15) * NPIX + n] = o0[r];
        Opart[(base + 16 + l15) * NPIX + n] = o1[r];
        if (l15 == 0) lpart[((size_t)(bh * SPLIT + s)) * NPIX + n] = ls[r];
    }
}

// ============ K3: reduce splits + normalize + proj (MFMA) + residual ===========
// grid (128, NB), block 256. Block handles 32 px.
__global__ __launch_bounds__(256) void k_projred(
    const float* __restrict__ x, const float* __restrict__ Opart,
    const float* __restrict__ lpart, const short* __restrict__ projwbf,
    const float* __restrict__ bias, float* __restrict__ x1)
{
    int px0 = blockIdx.x * 32;
    int b = blockIdx.y;
    int t = threadIdx.x;
    int w = t >> 6, lane = t & 63, l15 = lane & 15, quad = lane >> 4;

    __shared__ __align__(16) short Ash[32][72];   // bf16 A rows [px][k=48+16pad]
    __shared__ float rlsh[2][32];

    // per-(head,px) normalizer
    if (t < 64) {
        int h = t >> 5, px = t & 31;
        float l = 0.f;
#pragma unroll
        for (int s = 0; s < SPLIT; s++)
            l += lpart[((size_t)((b * 2 + h) * SPLIT + s)) * NPIX + px0 + px];
        rlsh[h][px] = 1.f / l;
    }
    // zero the k-pad region (c=48..63): 32px x 16 shorts = 256 dwords
    {
        int px = t & 31, j = t >> 5;       // j 0..7
        *(unsigned*)&Ash[px][48 + j * 2] = 0u;
    }
    __syncthreads();
    // cooperative reduce over splits -> normalized bf16 A tile
#pragma unroll
    for (int pi = 0; pi < 6; pi++) {
        int idx = pi * 256 + t;
        int px = idx & 31, c = idx >> 5;   // c 0..47
        int h = c / 24, ch = c % 24;
        float acc = 0.f;
#pragma unroll
        for (int s = 0; s < SPLIT; s++)
            acc += Opart[(((size_t)((b * 2 + h) * SPLIT + s)) * 32 + ch) * NPIX + px0 + px];
        Ash[px][c] = f2bf(acc * rlsh[h][px]);
    }
    __syncthreads();
    // proj via MFMA: 2 px-tiles x 3 oc-tiles = 6 jobs over 4 waves
    floatx4 zf = {0.f, 0.f, 0.f, 0.f};
    for (int job = w; job < 6; job += 4) {
        int pt = job / 3, ot = job % 3;
        short8 a0 = *(const short8*)&Ash[pt * 16 + l15][quad * 8];
        short8 a1 = *(const short8*)&Ash[pt * 16 + l15][32 + quad * 8];
        const short* wb = projwbf + (ot * 16 + l15) * 64;
        short8 b0 = *(const short8*)(wb + quad * 8);
        short8 b1 = *(const short8*)(wb + 32 + quad * 8);
        floatx4 c = __builtin_amdgcn_mfma_f32_16x16x32_bf16(a0, b0, zf, 0, 0, 0);
        c = __builtin_amdgcn_mfma_f32_16x16x32_bf16(a1, b1, c, 0, 0, 0);
        int oc = ot * 16 + l15;
        float bi = bias[oc];
#pragma unroll
        for (int r = 0; r < 4; r++) {
            int n = px0 + pt * 16 + quad * 4 + r;
            size_t idx = ((size_t)b * 48 + oc) * NPIX + n;
            x1[idx] = x[idx] + c[r] + bi;
        }
    }
}

// ============ K4: LN2 + fi 1x1 (MFMA) + dw3 + GELU-gate + fo 1x1 (MFMA) + res ==
// Tile: interior 8x2, halo 10x4 = 40 px. grid (8,32,NB), block 256 (4 waves).
__global__ __launch_bounds__(256) void k_ffn(
    const float* __restrict__ x1, const float* __restrict__ lw, const float* __restrict__ lb,
    const short* __restrict__ fiwbf, const float* __restrict__ fib,
    const float* __restrict__ fdww, const float* __restrict__ fdwb,
    const short* __restrict__ fowbf, const float* __restrict__ fob,
    float* __restrict__ out)
{
    int ox = blockIdx.x * 8, oy = blockIdx.y * 2, b = blockIdx.z;
    int t = threadIdx.x;
    int w = t >> 6, lane = t & 63, l15 = lane & 15, quad = lane >> 4;

    __shared__ short xnbf[48][72];
    __shared__ float fp[48][196];
    __shared__ short yv[16][104];

    if (t < 48) {
        float v[48];
        if (t < 40) {
            int gx = ox + (t % 10) - 1, gy = oy + (t / 10) - 1;
            if ((unsigned)gx < 64u && (unsigned)gy < 64u) {
                int p = gy * 64 + gx;
                const float* xb = x1 + (size_t)b * DIMC * NPIX;
                float mu = 0.f;
#pragma unroll
                for (int c = 0; c < 48; c++) { v[c] = xb[c * NPIX + p]; mu += v[c]; }
                mu *= (1.f / 48.f);
                float var = 0.f;
#pragma unroll
                for (int c = 0; c < 48; c++) { float d = v[c] - mu; var += d * d; }
                var *= (1.f / 48.f);
                float rs = rsqrtf(var + 1e-5f);
#pragma unroll
                for (int c = 0; c < 48; c++) v[c] = (v[c] - mu) * rs * lw[c] + lb[c];
            } else {
#pragma unroll
                for (int c = 0; c < 48; c++) v[c] = 0.f;
            }
        } else {
#pragma unroll
            for (int c = 0; c < 48; c++) v[c] = 0.f;
        }
        unsigned* row = (unsigned*)&xnbf[t][0];
#pragma unroll
        for (int i = 0; i < 24; i++) {
            __hip_bfloat162 pk = __float22bfloat162_rn(make_float2(v[2 * i], v[2 * i + 1]));
            row[i] = *(unsigned*)&pk;
        }
#pragma unroll
        for (int i = 24; i < 36; i++) row[i] = 0u;
    }
    __syncthreads();
    floatx4 zf = {0.f, 0.f, 0.f, 0.f};
    for (int job = w; job < 36; job += 4) {
        int pt = job / 12, ot = job % 12;
        short8 a0 = *(const short8*)&xnbf[pt * 16 + l15][quad * 8];
        short8 a1 = *(const short8*)&xnbf[pt * 16 + l15][32 + quad * 8];
        const short* wb = fiwbf + (ot * 16 + l15) * 64;
        short8 b0 = *(const short8*)(wb + quad * 8);
        short8 b1 = *(const short8*)(wb + 32 + quad * 8);
        floatx4 c = __builtin_amdgcn_mfma_f32_16x16x32_bf16(a0, b0, zf, 0, 0, 0);
        c = __builtin_amdgcn_mfma_f32_16x16x32_bf16(a1, b1, c, 0, 0, 0);
        float bi = fib[ot * 16 + l15];
#pragma unroll
        for (int r = 0; r < 4; r++) {
            int hp = pt * 16 + quad * 4 + r;
            if (hp < 40) {
                int gx = ox + hp % 10 - 1, gy = oy + hp / 10 - 1;
                bool valid = (unsigned)gx < 64u && (unsigned)gy < 64u;
                fp[hp][ot * 16 + l15] = valid ? (c[r] + bi) : 0.f;
            }
        }
    }
    __syncthreads();
    for (int task = t; task < 16 * 96; task += 256) {
        int c = task % 96, px = task / 96;
        int hr = (px >> 3) * 10 + (px & 7) + 11;
        const float* wp = fdww + (size_t)c * 9;
        float a = fdwb[c];
        a += fp[hr - 11][c] * wp[0] + fp[hr - 10][c] * wp[1] + fp[hr - 9][c] * wp[2]
           + fp[hr - 1][c]  * wp[3] + fp[hr][c]      * wp[4] + fp[hr + 1][c] * wp[5]
           + fp[hr + 9][c]  * wp[6] + fp[hr + 10][c] * wp[7] + fp[hr + 11][c] * wp[8];
        int c2 = c + 96;
        const float* wp2 = fdww + (size_t)c2 * 9;
        float g2 = fdwb[c2];
        g2 += fp[hr - 11][c2] * wp2[0] + fp[hr - 10][c2] * wp2[1] + fp[hr - 9][c2] * wp2[2]
            + fp[hr - 1][c2]  * wp2[3] + fp[hr][c2]      * wp2[4] + fp[hr + 1][c2] * wp2[5]
            + fp[hr + 9][c2]  * wp2[6] + fp[hr + 10][c2] * wp2[7] + fp[hr + 11][c2] * wp2[8];
        float ge = 0.5f * a * (1.f + erff(a * 0.70710678118654752f));
        yv[px][c] = f2bf(ge * g2);
    }
    __syncthreads();
    if (w < 3) {
        int ot = w;
        floatx4 c = zf;
#pragma unroll
        for (int k = 0; k < 3; k++) {
            short8 a = *(const short8*)&yv[l15][k * 32 + quad * 8];
            short8 bb = *(const short8*)(fowbf + (ot * 16 + l15) * 96 + k * 32 + quad * 8);
            c = __builtin_amdgcn_mfma_f32_16x16x32_bf16(a, bb, c, 0, 0, 0);
        }
        int oc = ot * 16 + l15;
        float bi = fob[oc];
#pragma unroll
        for (int r = 0; r < 4; r++) {
            int px = quad * 4 + r;
            int n = (oy + (px >> 3)) * 64 + ox + (px & 7);
            size_t idx = ((size_t)b * 48 + oc) * NPIX + n;
            out[idx] = x1[idx] + c[r] + bi;
        }
    }
}

extern "C" void kernel_launch(void* const* d_in, const int* in_sizes, int n_in,
                              void* d_out, int out_size, void* d_ws, size_t ws_size,
                              hipStream_t stream) {
    const float* x       = (const float*)d_in[0];
    const float* n1w     = (const float*)d_in[1];
    const float* n1b     = (const float*)d_in[2];
    const float* qkv_w   = (const float*)d_in[3];
    const float* qkv_b   = (const float*)d_in[4];
    const float* qkvdw_w = (const float*)d_in[5];
    const float* qkvdw_b = (const float*)d_in[6];
    const float* temp    = (const float*)d_in[7];
    const float* proj_w  = (const float*)d_in[8];
    const float* proj_b  = (const float*)d_in[9];
    const float* n2w     = (const float*)d_in[10];
    const float* n2b     = (const float*)d_in[11];
    const float* fi_w    = (const float*)d_in[12];
    const float* fi_b    = (const float*)d_in[13];
    const float* fdw_w   = (const float*)d_in[14];
    const float* fdw_b   = (const float*)d_in[15];
    const float* fo_w    = (const float*)d_in[16];
    const float* fo_b    = (const float*)d_in[17];

    float* ws = (float*)d_ws;
    short* Qbf   = (short*)ws;                   // 524288 shorts
    short* Kbf   = Qbf + 524288;                 // 524288 shorts
    short* Vbf   = Kbf + 524288;                 // 524288 shorts (= 786432 floats)
    float* Opart = ws + 786432;                  // 4*8*32*4096 = 4194304 f
    float* lpart = Opart + 4194304;              // 4*8*4096 = 131072 f
    float* x1    = lpart + 131072;               // 393216 f
    short* qkvwbf = (short*)(x1 + 393216);       // 9216 shorts
    short* fiwbf  = qkvwbf + 9216;               // 12288 shorts
    short* fowbf  = fiwbf + 12288;               // 4608 shorts
    short* projwbf = fowbf + 4608;               // 3072 shorts

    {   // weights -> bf16 B-layout
        int total = 144 * 64 + 192 * 64 + 48 * 96 + 48 * 64;
        k_prepw<<<(total + 255) / 256, 256, 0, stream>>>(qkv_w, fi_w, fo_w, proj_w,
                                                         qkvwbf, fiwbf, fowbf, projwbf);
    }
    {   // LN1 + qkv1x1(MFMA) + dw3 + heads
        dim3 g(8, 32, NB);
        k_attnpre<<<g, 256, 0, stream>>>(x, n1w, n1b, qkvwbf, qkv_b, qkvdw_w, qkvdw_b,
                                         temp, Qbf, Kbf, Vbf);
    }
    {   // attention
        dim3 g(64, SPLIT, 4);
        k_attn_mfma<<<g, 256, 0, stream>>>(Qbf, Kbf, Vbf, Opart, lpart);
    }
    {   // reduce + proj(MFMA) + residual
        dim3 g(128, NB);
        k_projred<<<g, 256, 0, stream>>>(x, Opart, lpart, projwbf, proj_b, x1);
    }
    {   // LN2 + fi(MFMA) + dw3 + gate + fo(MFMA) + residual
        dim3 g(8, 32, NB);
        k_ffn<<<g, 256, 0, stream>>>(x1, n2w, n2b, fiwbf, fi_b, fdw_w, fdw_b,
                                     fowbf, fo_b, (float*)d_out);
    }
}